// Round 4
// baseline (425.041 us; speedup 1.0000x reference)
//
#include <hip/hip_runtime.h>
#include <hip/hip_bf16.h>

// LIF neuron update (SpikeLayer.update_neurons), one step.
// Elementwise over N = 64*256*32*32 fp32 elements.
// Outputs (concatenated in d_out): psp, mem_out, refrac_out, spiketrain_out.
//
// Constants from the reference config:
//   DT=1.0, TAU_REFRAC=2.0, V_THRESH=1.0, LEAK=true, TIME=5.0
//
// Note: the `spiketrain` input is dead (never read by the math) -> we do not
// load it, saving 67 MB of HBM fetch.

#define LIF_TIME        5.0f
#define LIF_TAU_REFRAC  2.0f
#define LIF_V_THRESH    1.0f
#define LIF_LEAK_DEC    0.1f   /* 0.1 * dt, dt = 1.0 */

__global__ __launch_bounds__(256) void lif_update_kernel(
    const float4* __restrict__ impulse,
    const float4* __restrict__ mem,
    const float4* __restrict__ refrac_until,
    float4* __restrict__ psp_out,
    float4* __restrict__ mem_out,
    float4* __restrict__ refrac_out,
    float4* __restrict__ spiketrain_out,
    int n4)
{
    const int stride = gridDim.x * blockDim.x;
    for (int i = blockIdx.x * blockDim.x + threadIdx.x; i < n4; i += stride) {
        const float4 imp = impulse[i];
        const float4 m   = mem[i];
        const float4 ru  = refrac_until[i];

        float4 psp, mo, ro, so;

        #pragma unroll
        for (int j = 0; j < 4; ++j) {
            const float impj = (&imp.x)[j];
            const float mj   = (&m.x)[j];
            const float ruj  = (&ru.x)[j];

            // masked impulse: zero while refractory
            float nm = mj + ((ruj > LIF_TIME) ? 0.0f : impj);
            // leak on positive membrane
            nm = (nm > 0.0f) ? (nm - LIF_LEAK_DEC) : nm;

            const bool spiked = (nm >= LIF_V_THRESH);

            (&psp.x)[j] = spiked ? LIF_V_THRESH : 0.0f;
            (&mo.x)[j]  = spiked ? 0.0f : nm;
            (&ro.x)[j]  = spiked ? (LIF_TIME + LIF_TAU_REFRAC) : ruj;
            (&so.x)[j]  = spiked ? LIF_TIME : 0.0f;
        }

        psp_out[i]        = psp;
        mem_out[i]        = mo;
        refrac_out[i]     = ro;
        spiketrain_out[i] = so;
    }
}

extern "C" void kernel_launch(void* const* d_in, const int* in_sizes, int n_in,
                              void* d_out, int out_size, void* d_ws, size_t ws_size,
                              hipStream_t stream) {
    (void)n_in; (void)d_ws; (void)ws_size;

    const float* impulse      = (const float*)d_in[0];
    const float* mem          = (const float*)d_in[1];
    const float* refrac_until = (const float*)d_in[2];
    // d_in[3] (spiketrain) is dead -> not read.

    const int n = in_sizes[0];          // 16,777,216
    float* out = (float*)d_out;         // 4*n elements, concatenated

    float* psp_out        = out;
    float* mem_out        = out + (size_t)n;
    float* refrac_out     = out + 2 * (size_t)n;
    float* spiketrain_out = out + 3 * (size_t)n;

    const int n4 = n / 4;               // N divisible by 4 (shape 64*256*32*32)

    const int block = 256;
    int grid = (n4 + block - 1) / block;
    const int max_grid = 2048;          // 256 CUs * 8 blocks, grid-stride rest
    if (grid > max_grid) grid = max_grid;

    lif_update_kernel<<<grid, block, 0, stream>>>(
        (const float4*)impulse, (const float4*)mem, (const float4*)refrac_until,
        (float4*)psp_out, (float4*)mem_out, (float4*)refrac_out,
        (float4*)spiketrain_out, n4);
}

// Round 5
// 423.657 us; speedup vs baseline: 1.0033x; 1.0033x over previous
//
#include <hip/hip_runtime.h>
#include <hip/hip_bf16.h>

// LIF neuron update (SpikeLayer.update_neurons), one step.
// Elementwise over N = 64*256*32*32 fp32 elements.
// Outputs (concatenated in d_out): psp, mem_out, refrac_out, spiketrain_out.
//
// Constants from the reference config:
//   DT=1.0, TAU_REFRAC=2.0, V_THRESH=1.0, LEAK=true, TIME=5.0
//
// The `spiketrain` input is dead (never read by the math) -> not loaded.
// Traffic: 3 reads + 4 writes x 67.1 MB = 470 MB -> ~75 us floor @ 6.3 TB/s.
//
// R4 evidence: harness fillBuffer hits 6.5 TB/s (81% peak) on this chip;
// our kernel dispatch was < 164 us (absent from top-5). This round: exact
// flat grid (16384 blocks, 1 float4/thread) instead of grid-stride x8 --
// graph replay amortizes launch cost, so the cap bought nothing.

#define LIF_TIME        5.0f
#define LIF_TAU_REFRAC  2.0f
#define LIF_V_THRESH    1.0f
#define LIF_LEAK_DEC    0.1f   /* 0.1 * dt, dt = 1.0 */

__global__ __launch_bounds__(256) void lif_update_kernel(
    const float4* __restrict__ impulse,
    const float4* __restrict__ mem,
    const float4* __restrict__ refrac_until,
    float4* __restrict__ psp_out,
    float4* __restrict__ mem_out,
    float4* __restrict__ refrac_out,
    float4* __restrict__ spiketrain_out,
    int n4)
{
    const int i = blockIdx.x * blockDim.x + threadIdx.x;
    if (i >= n4) return;

    const float4 imp = impulse[i];
    const float4 m   = mem[i];
    const float4 ru  = refrac_until[i];

    float4 psp, mo, ro, so;

    #pragma unroll
    for (int j = 0; j < 4; ++j) {
        const float impj = (&imp.x)[j];
        const float mj   = (&m.x)[j];
        const float ruj  = (&ru.x)[j];

        // masked impulse: zero while refractory
        float nm = mj + ((ruj > LIF_TIME) ? 0.0f : impj);
        // leak on positive membrane
        nm = (nm > 0.0f) ? (nm - LIF_LEAK_DEC) : nm;

        const bool spiked = (nm >= LIF_V_THRESH);

        (&psp.x)[j] = spiked ? LIF_V_THRESH : 0.0f;
        (&mo.x)[j]  = spiked ? 0.0f : nm;
        (&ro.x)[j]  = spiked ? (LIF_TIME + LIF_TAU_REFRAC) : ruj;
        (&so.x)[j]  = spiked ? LIF_TIME : 0.0f;
    }

    psp_out[i]        = psp;
    mem_out[i]        = mo;
    refrac_out[i]     = ro;
    spiketrain_out[i] = so;
}

extern "C" void kernel_launch(void* const* d_in, const int* in_sizes, int n_in,
                              void* d_out, int out_size, void* d_ws, size_t ws_size,
                              hipStream_t stream) {
    (void)n_in; (void)d_ws; (void)ws_size;

    const float* impulse      = (const float*)d_in[0];
    const float* mem          = (const float*)d_in[1];
    const float* refrac_until = (const float*)d_in[2];
    // d_in[3] (spiketrain) is dead -> not read.

    const int n = in_sizes[0];          // 16,777,216
    float* out = (float*)d_out;         // 4*n elements, concatenated

    float* psp_out        = out;
    float* mem_out        = out + (size_t)n;
    float* refrac_out     = out + 2 * (size_t)n;
    float* spiketrain_out = out + 3 * (size_t)n;

    const int n4 = n / 4;               // 4,194,304 (divisible)

    const int block = 256;
    const int grid = (n4 + block - 1) / block;   // 16384 blocks, exact

    lif_update_kernel<<<grid, block, 0, stream>>>(
        (const float4*)impulse, (const float4*)mem, (const float4*)refrac_until,
        (float4*)psp_out, (float4*)mem_out, (float4*)refrac_out,
        (float4*)spiketrain_out, n4);
}